// Round 1
// 308.120 us; speedup vs baseline: 1.0060x; 1.0060x over previous
//
#include <hip/hip_runtime.h>
#include <stdint.h>

// Problem constants (fixed by setup_inputs): B=8192, I=512, H=1024
#define BATCH 8192
#define IDIM  512
#define HDIM  1024
#define KDIM  1536          // I + H
#define NDIM  4096          // 4*H

typedef __bf16 bf16x8 __attribute__((ext_vector_type(8)));
typedef float  f32x4  __attribute__((ext_vector_type(4)));
typedef unsigned short u16x8 __attribute__((ext_vector_type(8)));

__device__ __forceinline__ unsigned short f2bf(float f) {
    union { float f; unsigned u; } v; v.f = f;
    unsigned r = v.u + 0x7fffu + ((v.u >> 16) & 1u);   // RNE
    return (unsigned short)(r >> 16);
}
__device__ __forceinline__ float bf2f(unsigned short u) {
    union { unsigned u; float f; } v; v.u = ((unsigned)u) << 16;
    return v.f;
}
__device__ __forceinline__ float fexp(float x) {      // e^x via v_exp_f32
    return __builtin_amdgcn_exp2f(x * 1.44269504f);
}
__device__ __forceinline__ float sigm(float x) {      // stable for |x| large
    return __builtin_amdgcn_rcpf(1.f + fexp(-x));
}
__device__ __forceinline__ float ftanh(float x) {     // 1 - 2/(e^{2x}+1)
    return 1.f - 2.f * __builtin_amdgcn_rcpf(1.f + fexp(2.f * x));
}

__device__ __forceinline__ void load16(void* lds, const void* g) {
    __builtin_amdgcn_global_load_lds(
        (const __attribute__((address_space(1))) unsigned int*)g,
        (__attribute__((address_space(3))) unsigned int*)lds, 16, 0, 0);
}

// ------------- Kernel 1: fused input packing ------------------------------
// blocks [0, NPACKA): pack [x|h] -> bf16 A (BATCH x KDIM)
// blocks [NPACKA, ..): transpose+convert [Wi;Wh] -> bf16 Wt (NDIM x KDIM)
#define NPACKA (BATCH * KDIM / 4 / 256)      // 12288
#define NPACKW ((NDIM / 32) * (KDIM / 32))   // 6144
__global__ __launch_bounds__(256) void pack_ab(const float* __restrict__ x,
                                               const float* __restrict__ h,
                                               const float* __restrict__ Wi,
                                               const float* __restrict__ Wh,
                                               unsigned short* __restrict__ A,
                                               unsigned short* __restrict__ Wt) {
    __shared__ float tile[32][33];
    int blk = blockIdx.x;
    if (blk < NPACKA) {
        int idx = blk * 256 + threadIdx.x;   // group of 4 elements
        int row = idx / (KDIM / 4);
        int g   = idx % (KDIM / 4);
        int col = g * 4;
        float4 v;
        if (col < IDIM) v = ((const float4*)(x + (size_t)row * IDIM))[g];
        else            v = ((const float4*)(h + (size_t)row * HDIM))[(col - IDIM) / 4];
        ushort4 o;
        o.x = f2bf(v.x); o.y = f2bf(v.y); o.z = f2bf(v.z); o.w = f2bf(v.w);
        ((ushort4*)A)[idx] = o;
    } else {
        int b  = blk - NPACKA;
        int n0 = (b & 127) * 32;             // column in W  (0..NDIM)
        int k0 = (b >> 7) * 32;              // row in W     (0..KDIM)
        int tx = threadIdx.x & 31, ty = threadIdx.x >> 5;   // 32 x 8
#pragma unroll
        for (int j = 0; j < 4; j++) {
            int k = k0 + ty + 8 * j;
            float v;
            if (k < IDIM) v = Wi[(size_t)k * NDIM + n0 + tx];
            else          v = Wh[(size_t)(k - IDIM) * NDIM + n0 + tx];
            tile[ty + 8 * j][tx] = v;
        }
        __syncthreads();
#pragma unroll
        for (int j = 0; j < 4; j++)
            Wt[(size_t)(n0 + ty + 8 * j) * KDIM + k0 + tx] = f2bf(tile[tx][ty + 8 * j]);
    }
}

// ---------------- Kernel 2: bf16 GEMM gates = A @ Wt^T (bf16 out) ----------
// 256x256 tile, BK=32, 8 waves (2M x 4N), 4-slot LDS ring (128 KB).
// Deep pipeline: stage tile T+3 while computing tile T; counted vmcnt(8) at
// the per-tile handoff (never 0 in steady state) keeps 2 K-tiles of
// global_load_lds in flight across barriers (T4). Raw s_barrier (no
// __syncthreads -> no vmcnt(0) drain). Two 16-MFMA phases per tile wrapped in
// setprio (T5). LDS linear (global_load_lds constraint); bank-conflict
// swizzle folded into the pre-swizzled GLOBAL source address:
//   LDS chunk (rp, s) holds data (row = 2rp + (x>>2), kchunk = x&3), x=s^(rp&7)
// -> each 16-lane b128 read phase hits all 8 bank-groups exactly 2x (free).
// Grid: 512 wgs, XCD-swizzled (bijective, 512%8==0), M-fastest.
__global__ __launch_bounds__(512, 2) void gemm_bt(const unsigned short* __restrict__ A,
                                                  const unsigned short* __restrict__ Bt,
                                                  unsigned short* __restrict__ C) {
    __shared__ __align__(16) unsigned short smem[65536];   // 128 KB: 4 x (A 16KB | B 16KB)

    const int t    = threadIdx.x;
    const int wave = t >> 6;
    const int lane = t & 63;
    const int lrow = lane & 15;
    const int quad = lane >> 4;

    const int bid = blockIdx.x;
    const int swz = (bid & 7) * 64 + (bid >> 3);   // XCD chunked, 512/8 = 64
    const int bm  = (swz & 31) * 256;              // M fastest (32 M-blocks)
    const int bn  = (swz >> 5) * 256;              // 16 N-blocks

    const int wm = (wave & 1) * 128;
    const int wn = (wave >> 1) * 64;

    // stage source offsets (shorts): swizzle folded into global source addr
    int srcA[2], srcB[2];
#pragma unroll
    for (int j = 0; j < 2; j++) {
        int q   = t + 512 * j;
        int rp  = q >> 3, s = q & 7;
        int xx  = s ^ (rp & 7);
        int row = 2 * rp + (xx >> 2);
        int kc  = xx & 3;
        srcA[j] = (bm + row) * KDIM + kc * 8;
        srcB[j] = (bn + row) * KDIM + kc * 8;
    }

    // ds_read fragment offsets (shorts), constant across tiles
    int offA[8], offB[4];
#pragma unroll
    for (int mt = 0; mt < 8; mt++) {
        int r = wm + mt * 16 + lrow;
        offA[mt] = (r >> 1) * 64 + (((((r & 1) << 2) | quad) ^ ((r >> 1) & 7)) * 8);
    }
#pragma unroll
    for (int nt = 0; nt < 4; nt++) {
        int r = wn + nt * 16 + lrow;
        offB[nt] = (r >> 1) * 64 + (((((r & 1) << 2) | quad) ^ ((r >> 1) & 7)) * 8);
    }

    f32x4 acc[8][4] = {};

#define STAGE(tt) do {                                              \
    unsigned short* _d = smem + (((tt) & 3) << 14);                 \
    const int _ko = (tt) * 32;                                      \
    load16(_d +          t * 8, A  + (size_t)(srcA[0] + _ko));      \
    load16(_d +  4096 +  t * 8, A  + (size_t)(srcA[1] + _ko));      \
    load16(_d +  8192 +  t * 8, Bt + (size_t)(srcB[0] + _ko));      \
    load16(_d + 12288 +  t * 8, Bt + (size_t)(srcB[1] + _ko));      \
} while (0)

    STAGE(0); STAGE(1); STAGE(2);

    const int NT = KDIM / 32;          // 48
    for (int T = 0; T < NT; ++T) {
        // handoff: force tile T's 4 loads (per thread) complete; keep the
        // rest (up to 8 = tiles T+1,T+2) in flight. Drain 8->4->0 at tail.
        if (T < NT - 2)       asm volatile("s_waitcnt vmcnt(8)" ::: "memory");
        else if (T == NT - 2) asm volatile("s_waitcnt vmcnt(4)" ::: "memory");
        else                  asm volatile("s_waitcnt vmcnt(0)" ::: "memory");
        __builtin_amdgcn_s_barrier();
        asm volatile("" ::: "memory");   // pin ds_reads/stages below barrier

        const unsigned short* bufA = smem + ((T & 3) << 14);
        const unsigned short* bufB = bufA + 8192;

        // phase 0: read a0..3, b0..3; issue next stage; 16 MFMA
        bf16x8 a[4], b[4];
#pragma unroll
        for (int i = 0; i < 4; i++) a[i] = *(const bf16x8*)(bufA + offA[i]);
#pragma unroll
        for (int i = 0; i < 4; i++) b[i] = *(const bf16x8*)(bufB + offB[i]);
        if (T + 3 < NT) STAGE(T + 3);   // writes slot (T-1)&3: freed by barrier

        __builtin_amdgcn_s_barrier();
        __builtin_amdgcn_s_setprio(1);
#pragma unroll
        for (int mt = 0; mt < 4; mt++)
#pragma unroll
            for (int nt = 0; nt < 4; nt++)
                acc[mt][nt] = __builtin_amdgcn_mfma_f32_16x16x32_bf16(
                    a[mt], b[nt], acc[mt][nt], 0, 0, 0);
        __builtin_amdgcn_s_setprio(0);
        __builtin_amdgcn_s_barrier();

        // phase 1: read a4..7 (reuse b); 16 MFMA
        bf16x8 a2[4];
#pragma unroll
        for (int i = 0; i < 4; i++) a2[i] = *(const bf16x8*)(bufA + offA[4 + i]);

        __builtin_amdgcn_s_barrier();
        __builtin_amdgcn_s_setprio(1);
#pragma unroll
        for (int mt = 0; mt < 4; mt++)
#pragma unroll
            for (int nt = 0; nt < 4; nt++)
                acc[4 + mt][nt] = __builtin_amdgcn_mfma_f32_16x16x32_bf16(
                    a2[mt], b[nt], acc[4 + mt][nt], 0, 0, 0);
        __builtin_amdgcn_s_setprio(0);
    }
#undef STAGE

#pragma unroll
    for (int mt = 0; mt < 8; mt++)
#pragma unroll
        for (int nt = 0; nt < 4; nt++) {
            int row = bm + wm + mt * 16 + quad * 4;
            int col = bn + wn + nt * 16 + lrow;
#pragma unroll
            for (int r = 0; r < 4; r++)
                C[(size_t)(row + r) * NDIM + col] = f2bf(acc[mt][nt][r]);
        }
}

// ---------------- Kernel 3: per-row LN + LSTM epilogue ---------------------
// One WAVE per batch row (4 rows/block). Lane l owns columns [16l,16l+16) of
// all 4 gates -> the 4 LN reductions are full-wave shuffle reductions and the
// i/f/g/o combine is intra-lane. No LDS, no __syncthreads.
__global__ __launch_bounds__(256) void lstm_ep(const unsigned short* __restrict__ gates,
                                               const float* __restrict__ bh,
                                               const float* __restrict__ c,
                                               const float* __restrict__ gamma,
                                               const float* __restrict__ beta,
                                               float* __restrict__ out) {
    const int wave = threadIdx.x >> 6;
    const int lane = threadIdx.x & 63;
    const int b    = blockIdx.x * 4 + wave;
    const int col0 = lane * 16;

    const unsigned short* gr = gates + (size_t)b * NDIM;
    float v[4][16];
    float s[4], sq[4];
#pragma unroll
    for (int g = 0; g < 4; g++) {
        const unsigned short* gp = gr + g * HDIM + col0;
        u16x8 ga = *(const u16x8*)gp;
        u16x8 gb = *(const u16x8*)(gp + 8);
        float bb[16];
#pragma unroll
        for (int q = 0; q < 4; q++)
            *(float4*)(bb + 4 * q) = ((const float4*)(bh + g * HDIM + col0))[q];
        float ls = 0.f, lq = 0.f;
#pragma unroll
        for (int j = 0; j < 16; j++) {
            float tv = bf2f(j < 8 ? ga[j] : gb[j - 8]) + bb[j];
            v[g][j] = tv; ls += tv; lq += tv * tv;
        }
        s[g] = ls; sq[g] = lq;
    }
#pragma unroll
    for (int off = 32; off; off >>= 1) {
#pragma unroll
        for (int g = 0; g < 4; g++) {
            s[g]  += __shfl_xor(s[g], off);
            sq[g] += __shfl_xor(sq[g], off);
        }
    }
#pragma unroll
    for (int g = 0; g < 4; g++) {
        const float mu  = s[g] * (1.f / HDIM);
        const float var = sq[g] * (1.f / HDIM) - mu * mu;
        const float rs  = rsqrtf(var + 1e-5f);
        float gm[16], bt[16];
#pragma unroll
        for (int q = 0; q < 4; q++) {
            *(float4*)(gm + 4 * q) = ((const float4*)(gamma + g * HDIM + col0))[q];
            *(float4*)(bt + 4 * q) = ((const float4*)(beta  + g * HDIM + col0))[q];
        }
#pragma unroll
        for (int j = 0; j < 16; j++) {
            float y = (v[g][j] - mu) * rs * gm[j] + bt[j];
            v[g][j] = (g == 2) ? ftanh(y) : sigm(y);
        }
    }
    const size_t base = (size_t)b * HDIM + col0;
#pragma unroll
    for (int q = 0; q < 4; q++) {
        float4 ci = *(const float4*)(c + base + 4 * q);
        float4 cn, hn;
#pragma unroll
        for (int e = 0; e < 4; e++) {
            int j = 4 * q + e;
            float cnv = v[1][j] * ((float*)&ci)[e] + v[0][j] * v[2][j];
            ((float*)&cn)[e] = cnv;
            ((float*)&hn)[e] = v[3][j] * ftanh(cnv);
        }
        *(float4*)(out + base + 4 * q) = hn;                               // h_new
        *(float4*)(out + (size_t)BATCH * HDIM + base + 4 * q) = cn;        // c_new
    }
}

extern "C" void kernel_launch(void* const* d_in, const int* in_sizes, int n_in,
                              void* d_out, int out_size, void* d_ws, size_t ws_size,
                              hipStream_t stream) {
    const float* x     = (const float*)d_in[0];
    const float* h     = (const float*)d_in[1];
    const float* c     = (const float*)d_in[2];
    const float* Wi    = (const float*)d_in[3];
    const float* Wh    = (const float*)d_in[4];
    const float* bh    = (const float*)d_in[5];
    const float* gamma = (const float*)d_in[6];
    const float* beta  = (const float*)d_in[7];
    float* out = (float*)d_out;

    // workspace layout
    unsigned short* A  = (unsigned short*)d_ws;                                        // 25.2 MB
    unsigned short* Wt = (unsigned short*)((char*)d_ws + (size_t)BATCH * KDIM * 2);    // 12.6 MB
    unsigned short* gates = (unsigned short*)((char*)d_ws + (size_t)BATCH * KDIM * 2
                                                          + (size_t)NDIM * KDIM * 2); // 64 MB

    pack_ab<<<NPACKA + NPACKW, 256, 0, stream>>>(x, h, Wi, Wh, A, Wt);
    gemm_bt<<<dim3((BATCH / 256) * (NDIM / 256)), 512, 0, stream>>>(A, Wt, gates);
    lstm_ep<<<BATCH / 4, 256, 0, stream>>>(gates, bh, c, gamma, beta, out);
}

// Round 2
// 296.292 us; speedup vs baseline: 1.0461x; 1.0399x over previous
//
#include <hip/hip_runtime.h>
#include <stdint.h>

// Problem constants (fixed by setup_inputs): B=8192, I=512, H=1024
#define BATCH 8192
#define IDIM  512
#define HDIM  1024
#define KDIM  1536          // I + H
#define NDIM  4096          // 4*H

typedef __bf16 bf16x8 __attribute__((ext_vector_type(8)));
typedef float  f32x4  __attribute__((ext_vector_type(4)));
typedef unsigned short u16x8 __attribute__((ext_vector_type(8)));

__device__ __forceinline__ unsigned short f2bf(float f) {
    union { float f; unsigned u; } v; v.f = f;
    unsigned r = v.u + 0x7fffu + ((v.u >> 16) & 1u);   // RNE
    return (unsigned short)(r >> 16);
}
__device__ __forceinline__ float bf2f(unsigned short u) {
    union { unsigned u; float f; } v; v.u = ((unsigned)u) << 16;
    return v.f;
}
__device__ __forceinline__ float fexp(float x) {      // e^x via v_exp_f32
    return __builtin_amdgcn_exp2f(x * 1.44269504f);
}
__device__ __forceinline__ float sigm(float x) {      // stable for |x| large
    return __builtin_amdgcn_rcpf(1.f + fexp(-x));
}
__device__ __forceinline__ float ftanh(float x) {     // 1 - 2/(e^{2x}+1)
    return 1.f - 2.f * __builtin_amdgcn_rcpf(1.f + fexp(2.f * x));
}

__device__ __forceinline__ void load16(void* lds, const void* g) {
    __builtin_amdgcn_global_load_lds(
        (const __attribute__((address_space(1))) unsigned int*)g,
        (__attribute__((address_space(3))) unsigned int*)lds, 16, 0, 0);
}

// ------------- Kernel 1: fused input packing ------------------------------
// blocks [0, NPACKA): pack [x|h] -> bf16 A (BATCH x KDIM)
// blocks [NPACKA, ..): transpose+convert [Wi;Wh] -> bf16 Wt (NDIM x KDIM)
#define NPACKA (BATCH * KDIM / 4 / 256)      // 12288
#define NPACKW ((NDIM / 32) * (KDIM / 32))   // 6144
__global__ __launch_bounds__(256) void pack_ab(const float* __restrict__ x,
                                               const float* __restrict__ h,
                                               const float* __restrict__ Wi,
                                               const float* __restrict__ Wh,
                                               unsigned short* __restrict__ A,
                                               unsigned short* __restrict__ Wt) {
    __shared__ float tile[32][33];
    int blk = blockIdx.x;
    if (blk < NPACKA) {
        int idx = blk * 256 + threadIdx.x;   // group of 4 elements
        int row = idx / (KDIM / 4);
        int g   = idx % (KDIM / 4);
        int col = g * 4;
        float4 v;
        if (col < IDIM) v = ((const float4*)(x + (size_t)row * IDIM))[g];
        else            v = ((const float4*)(h + (size_t)row * HDIM))[(col - IDIM) / 4];
        ushort4 o;
        o.x = f2bf(v.x); o.y = f2bf(v.y); o.z = f2bf(v.z); o.w = f2bf(v.w);
        ((ushort4*)A)[idx] = o;
    } else {
        int b  = blk - NPACKA;
        int n0 = (b & 127) * 32;             // column in W  (0..NDIM)
        int k0 = (b >> 7) * 32;              // row in W     (0..KDIM)
        int tx = threadIdx.x & 31, ty = threadIdx.x >> 5;   // 32 x 8
#pragma unroll
        for (int j = 0; j < 4; j++) {
            int k = k0 + ty + 8 * j;
            float v;
            if (k < IDIM) v = Wi[(size_t)k * NDIM + n0 + tx];
            else          v = Wh[(size_t)(k - IDIM) * NDIM + n0 + tx];
            tile[ty + 8 * j][tx] = v;
        }
        __syncthreads();
#pragma unroll
        for (int j = 0; j < 4; j++)
            Wt[(size_t)(n0 + ty + 8 * j) * KDIM + k0 + tx] = f2bf(tile[tx][ty + 8 * j]);
    }
}

// ---------------- Kernel 2: bf16 GEMM gates = A @ Wt^T (bf16 out) ----------
// 256x256 tile, BK=32, 8 waves (2M x 4N), 4-slot LDS ring (128 KB).
// R2 change: NO mid-tile barriers (they forced 8-wave lockstep -> LDS-read
// pipe and MFMA pipe ran fully serialized: 1242+1152 cyc/tile measured).
// Only the once-per-tile handoff barrier (ring correctness) remains. All 12
// fragment ds_read_b128 issue BEFORE the MFMA clusters (sched_barrier(0)
// region pins); compiler emits counted lgkmcnt(4)/(0) so MFMA0 runs while
// a2 reads execute; with no rendezvous between MFMA clusters the 2 waves/SIMD
// drift and overlap reads with each other's MFMAs.
// XCD swizzle: each XCD owns 4 contiguous M-panels (A slice 3.1MB ->
// L2-resident) x all 16 N -> FETCH should drop ~202->~140MB.
__global__ __launch_bounds__(512, 2) void gemm_bt(const unsigned short* __restrict__ A,
                                                  const unsigned short* __restrict__ Bt,
                                                  unsigned short* __restrict__ C) {
    __shared__ __align__(16) unsigned short smem[65536];   // 128 KB: 4 x (A 16KB | B 16KB)

    const int t    = threadIdx.x;
    const int wave = t >> 6;
    const int lane = t & 63;
    const int lrow = lane & 15;
    const int quad = lane >> 4;

    const int bid = blockIdx.x;
    const int xcd = bid & 7;
    const int j   = bid >> 3;                      // 0..63 within XCD
    const int bm  = (xcd * 4 + (j & 3)) * 256;     // XCD owns 4 M-panels
    const int bn  = (j >> 2) * 256;                // 16 N-panels

    const int wm = (wave & 1) * 128;
    const int wn = (wave >> 1) * 64;

    // stage source offsets (shorts): bank swizzle folded into global src addr
    int srcA[2], srcB[2];
#pragma unroll
    for (int jj = 0; jj < 2; jj++) {
        int q   = t + 512 * jj;
        int rp  = q >> 3, s = q & 7;
        int xx  = s ^ (rp & 7);
        int row = 2 * rp + (xx >> 2);
        int kc  = xx & 3;
        srcA[jj] = (bm + row) * KDIM + kc * 8;
        srcB[jj] = (bn + row) * KDIM + kc * 8;
    }

    // ds_read fragment offsets (shorts), constant across tiles
    int offA[8], offB[4];
#pragma unroll
    for (int mt = 0; mt < 8; mt++) {
        int r = wm + mt * 16 + lrow;
        offA[mt] = (r >> 1) * 64 + (((((r & 1) << 2) | quad) ^ ((r >> 1) & 7)) * 8);
    }
#pragma unroll
    for (int nt = 0; nt < 4; nt++) {
        int r = wn + nt * 16 + lrow;
        offB[nt] = (r >> 1) * 64 + (((((r & 1) << 2) | quad) ^ ((r >> 1) & 7)) * 8);
    }

    f32x4 acc[8][4] = {};

#define STAGE(tt) do {                                              \
    unsigned short* _d = smem + (((tt) & 3) << 14);                 \
    const int _ko = (tt) * 32;                                      \
    load16(_d +          t * 8, A  + (size_t)(srcA[0] + _ko));      \
    load16(_d +  4096 +  t * 8, A  + (size_t)(srcA[1] + _ko));      \
    load16(_d +  8192 +  t * 8, Bt + (size_t)(srcB[0] + _ko));      \
    load16(_d + 12288 +  t * 8, Bt + (size_t)(srcB[1] + _ko));      \
} while (0)

    STAGE(0); STAGE(1); STAGE(2);

    const int NT = KDIM / 32;          // 48
    for (int T = 0; T < NT; ++T) {
        // handoff: tile T's 4 staging loads (per thread) must be done; keep
        // tiles T+1,T+2 (8 loads) in flight. Drain 8->4->0 only at the tail.
        if (T < NT - 2)       asm volatile("s_waitcnt vmcnt(8)" ::: "memory");
        else if (T == NT - 2) asm volatile("s_waitcnt vmcnt(4)" ::: "memory");
        else                  asm volatile("s_waitcnt vmcnt(0)" ::: "memory");
        __builtin_amdgcn_s_barrier();
        asm volatile("" ::: "memory");   // fence: no LDS reads hoist above

        const unsigned short* bufA = smem + ((T & 3) << 14);
        const unsigned short* bufB = bufA + 8192;

        // ---- issue ALL fragment reads up front (12 x ds_read_b128) -------
        bf16x8 a[4], b[4], a2[4];
#pragma unroll
        for (int i = 0; i < 4; i++) a[i] = *(const bf16x8*)(bufA + offA[i]);
#pragma unroll
        for (int i = 0; i < 4; i++) b[i] = *(const bf16x8*)(bufB + offB[i]);
        __builtin_amdgcn_sched_barrier(0);   // a,b group issues first
        if (T + 3 < NT) STAGE(T + 3);        // slot (T-1)&3: freed by barrier
#pragma unroll
        for (int i = 0; i < 4; i++) a2[i] = *(const bf16x8*)(bufA + offA[4 + i]);
        __builtin_amdgcn_sched_barrier(0);   // all reads pinned above MFMAs

        // ---- MFMA cluster 0: waits lgkmcnt(4) (a2 still in flight) -------
        __builtin_amdgcn_s_setprio(1);
#pragma unroll
        for (int mt = 0; mt < 4; mt++)
#pragma unroll
            for (int nt = 0; nt < 4; nt++)
                acc[mt][nt] = __builtin_amdgcn_mfma_f32_16x16x32_bf16(
                    a[mt], b[nt], acc[mt][nt], 0, 0, 0);
        __builtin_amdgcn_sched_barrier(0);   // keep cluster 1 after cluster 0

        // ---- MFMA cluster 1: waits lgkmcnt(0) for a2 ---------------------
#pragma unroll
        for (int mt = 0; mt < 4; mt++)
#pragma unroll
            for (int nt = 0; nt < 4; nt++)
                acc[4 + mt][nt] = __builtin_amdgcn_mfma_f32_16x16x32_bf16(
                    a2[mt], b[nt], acc[4 + mt][nt], 0, 0, 0);
        __builtin_amdgcn_s_setprio(0);
        asm volatile("" ::: "memory");       // reads stay inside this tile
    }
#undef STAGE

#pragma unroll
    for (int mt = 0; mt < 8; mt++)
#pragma unroll
        for (int nt = 0; nt < 4; nt++) {
            int row = bm + wm + mt * 16 + quad * 4;
            int col = bn + wn + nt * 16 + lrow;
#pragma unroll
            for (int r = 0; r < 4; r++)
                C[(size_t)(row + r) * NDIM + col] = f2bf(acc[mt][nt][r]);
        }
}

// ---------------- Kernel 3: per-row LN + LSTM epilogue ---------------------
// One WAVE per batch row (4 rows/block). Lane l owns columns [16l,16l+16) of
// all 4 gates -> the 4 LN reductions are full-wave shuffle reductions and the
// i/f/g/o combine is intra-lane. No LDS, no __syncthreads.
__global__ __launch_bounds__(256) void lstm_ep(const unsigned short* __restrict__ gates,
                                               const float* __restrict__ bh,
                                               const float* __restrict__ c,
                                               const float* __restrict__ gamma,
                                               const float* __restrict__ beta,
                                               float* __restrict__ out) {
    const int wave = threadIdx.x >> 6;
    const int lane = threadIdx.x & 63;
    const int b    = blockIdx.x * 4 + wave;
    const int col0 = lane * 16;

    const unsigned short* gr = gates + (size_t)b * NDIM;
    float v[4][16];
    float s[4], sq[4];
#pragma unroll
    for (int g = 0; g < 4; g++) {
        const unsigned short* gp = gr + g * HDIM + col0;
        u16x8 ga = *(const u16x8*)gp;
        u16x8 gb = *(const u16x8*)(gp + 8);
        float bb[16];
#pragma unroll
        for (int q = 0; q < 4; q++)
            *(float4*)(bb + 4 * q) = ((const float4*)(bh + g * HDIM + col0))[q];
        float ls = 0.f, lq = 0.f;
#pragma unroll
        for (int j = 0; j < 16; j++) {
            float tv = bf2f(j < 8 ? ga[j] : gb[j - 8]) + bb[j];
            v[g][j] = tv; ls += tv; lq += tv * tv;
        }
        s[g] = ls; sq[g] = lq;
    }
#pragma unroll
    for (int off = 32; off; off >>= 1) {
#pragma unroll
        for (int g = 0; g < 4; g++) {
            s[g]  += __shfl_xor(s[g], off);
            sq[g] += __shfl_xor(sq[g], off);
        }
    }
#pragma unroll
    for (int g = 0; g < 4; g++) {
        const float mu  = s[g] * (1.f / HDIM);
        const float var = sq[g] * (1.f / HDIM) - mu * mu;
        const float rs  = rsqrtf(var + 1e-5f);
        float gm[16], bt[16];
#pragma unroll
        for (int q = 0; q < 4; q++) {
            *(float4*)(gm + 4 * q) = ((const float4*)(gamma + g * HDIM + col0))[q];
            *(float4*)(bt + 4 * q) = ((const float4*)(beta  + g * HDIM + col0))[q];
        }
#pragma unroll
        for (int j = 0; j < 16; j++) {
            float y = (v[g][j] - mu) * rs * gm[j] + bt[j];
            v[g][j] = (g == 2) ? ftanh(y) : sigm(y);
        }
    }
    const size_t base = (size_t)b * HDIM + col0;
#pragma unroll
    for (int q = 0; q < 4; q++) {
        float4 ci = *(const float4*)(c + base + 4 * q);
        float4 cn, hn;
#pragma unroll
        for (int e = 0; e < 4; e++) {
            int j = 4 * q + e;
            float cnv = v[1][j] * ((float*)&ci)[e] + v[0][j] * v[2][j];
            ((float*)&cn)[e] = cnv;
            ((float*)&hn)[e] = v[3][j] * ftanh(cnv);
        }
        *(float4*)(out + base + 4 * q) = hn;                               // h_new
        *(float4*)(out + (size_t)BATCH * HDIM + base + 4 * q) = cn;        // c_new
    }
}

extern "C" void kernel_launch(void* const* d_in, const int* in_sizes, int n_in,
                              void* d_out, int out_size, void* d_ws, size_t ws_size,
                              hipStream_t stream) {
    const float* x     = (const float*)d_in[0];
    const float* h     = (const float*)d_in[1];
    const float* c     = (const float*)d_in[2];
    const float* Wi    = (const float*)d_in[3];
    const float* Wh    = (const float*)d_in[4];
    const float* bh    = (const float*)d_in[5];
    const float* gamma = (const float*)d_in[6];
    const float* beta  = (const float*)d_in[7];
    float* out = (float*)d_out;

    // workspace layout
    unsigned short* A  = (unsigned short*)d_ws;                                        // 25.2 MB
    unsigned short* Wt = (unsigned short*)((char*)d_ws + (size_t)BATCH * KDIM * 2);    // 12.6 MB
    unsigned short* gates = (unsigned short*)((char*)d_ws + (size_t)BATCH * KDIM * 2
                                                          + (size_t)NDIM * KDIM * 2); // 64 MB

    pack_ab<<<NPACKA + NPACKW, 256, 0, stream>>>(x, h, Wi, Wh, A, Wt);
    gemm_bt<<<dim3((BATCH / 256) * (NDIM / 256)), 512, 0, stream>>>(A, Wt, gates);
    lstm_ep<<<BATCH / 4, 256, 0, stream>>>(gates, bh, c, gamma, beta, out);
}